// Round 6
// baseline (367.756 us; speedup 1.0000x reference)
//
#include <hip/hip_runtime.h>
#include <cfloat>
#include <math.h>

namespace {
constexpr int Bn = 4, Cin = 8, Pn = 12000, Nn = 64, Co = 64, Hh = 282, Ww = 282;
constexpr int NPIL  = Bn * Pn;
constexpr int NCELL = Hh * Ww;
constexpr int CHW   = Pn * Nn;
constexpr double CNTD = (double)Bn * Pn * Nn;
constexpr int K1B = 1024;               // k1_mom blocks per input (8 waves/SIMD)
constexpr int WLU_CAP = 96000;          // union worklist cap (<= 48000 per input)
constexpr int FILL_B = (Bn * Co * NCELL / 4) / 256;   // 19881, exact

// Workspace layout. part (k1_mom partials) aliases the feats region: it is
// dead after k1b_reduce, before k5f_feat writes feats.
constexpr size_t PAR_OFF  = 0;                          // 2*576 floats = 4608
constexpr size_t MOM_OFF  = 4608;                       // 88 doubles   = 704
constexpr size_t HDR_OFF  = 5376;                       // 4 ints
constexpr size_t WLU_OFF  = 8192;                       // WLU_CAP int2 = 768000
constexpr size_t WIN_OFF  = WLU_OFF + (size_t)WLU_CAP * 8;   // 776192
constexpr size_t FEAT_OFF = WIN_OFF + (size_t)2 * Bn * NCELL * 4; // 3320960
constexpr size_t PART_OFF = FEAT_OFF;                   // alias (see above)
constexpr size_t WS_NEED  = FEAT_OFF + (size_t)2 * NPIL * 64 * 4; // 27896960

typedef __attribute__((ext_vector_type(8))) float f32x8_t;
typedef __attribute__((ext_vector_type(2))) float f32x2_t;

// Grid mapping matched to XLA's canonicalization: division by 0.16 becomes
// multiplication by the EXACT reciprocal 6.25 (rcp(0.16f) rounds to 6.25f).
// f32-div differs by ~0.3ulp -> O(1) pillars land one cell off (the 2.62 bug).
__device__ __forceinline__ int cell_of(float xc, float yc) {
  int xg = (int)floorf((xc + 22.0f) * 6.25f);
  int yg = (int)floorf((yc + 22.0f) * 6.25f);
  xg = min(max(xg, 0), Ww - 1);
  yg = min(max(yg, 0), Hh - 1);
  return yg * Ww + xg;
}

__device__ __forceinline__ float firstlane(float v) {
  return __int_as_float(__builtin_amdgcn_readfirstlane(__float_as_int(v)));
}
}

__global__ void kdiag(float* __restrict__ out, float v) {
  if (threadIdx.x == 0 && blockIdx.x == 0) out[0] = v;
}

// Merged bias-fill (blocks [0,FILL_B)) + winners/hdr init (blocks >= FILL_B).
__global__ __launch_bounds__(256) void kinit_fill(
    const float* __restrict__ b_bb, float* __restrict__ out,
    int* __restrict__ winners, int* __restrict__ hdr)
{
  if (blockIdx.x < FILL_B) {
    const int idx = blockIdx.x * 256 + threadIdx.x;
    const int plane = idx / (NCELL / 4);      // b*Co + o
    const float v = b_bb[plane & 63];
    ((float4*)out)[idx] = make_float4(v, v, v, v);
  } else {
    const int t = (blockIdx.x - FILL_B) * 256 + threadIdx.x;
    if (t < 4) hdr[t] = 0;
    for (int i = t; i < 2 * Bn * NCELL; i += 256 * 256) winners[i] = -1;
  }
}

// Merged over both inputs: blocks [0,K1B) -> sweep, [K1B,2*K1B) -> map.
// Memory-bound streaming pass; pillar->cell scatter fused in (lane 0 already
// holds xc/yc): one atomicMax per pillar.
__global__ __launch_bounds__(256) void k1_mom(
    const float* __restrict__ sweep, const float* __restrict__ map_in,
    float* __restrict__ partOut, int* __restrict__ winners)
{
  __shared__ float red[4][44];
  const int lane = threadIdx.x & 63;
  const int wv   = threadIdx.x >> 6;
  const int bid2 = blockIdx.x & (K1B - 1);
  const int inp  = blockIdx.x / K1B;
  const float* x = inp ? map_in : sweep;
  int* win = winners + inp * Bn * NCELL;
  const int gw   = (bid2 * 256 + (int)threadIdx.x) >> 6;
  const int nw   = (K1B * 256) >> 6;

  float sacc[8];
  float macc[36];
#pragma unroll
  for (int i = 0; i < 8; ++i) sacc[i] = 0.f;
#pragma unroll
  for (int i = 0; i < 36; ++i) macc[i] = 0.f;

  for (int pp = gw; pp < NPIL; pp += nw) {
    const int b = pp / Pn;
    const int p = pp - b * Pn;
    const float* xb = x + (size_t)b * Cin * CHW + (size_t)p * Nn + lane;
    float xv[Cin];
#pragma unroll
    for (int c = 0; c < Cin; ++c) xv[c] = xb[(size_t)c * CHW];
#pragma unroll
    for (int c = 0; c < Cin; ++c) sacc[c] += xv[c];
    {
      int k = 0;
#pragma unroll
      for (int i = 0; i < 8; ++i)
#pragma unroll
        for (int j = i; j < 8; ++j) { macc[k] = fmaf(xv[i], xv[j], macc[k]); ++k; }
    }
    // Fused scatter: xc = x[base] = lane 0's xv[0], yc = lane 0's xv[1].
    const float xc = firstlane(xv[0]);
    if (xc != 0.0f) {
      const float yc = firstlane(xv[1]);
      if (lane == 0) atomicMax(&win[b * NCELL + cell_of(xc, yc)], p);
    }
  }

#pragma unroll
  for (int k = 0; k < 44; ++k) {
    float v = (k < 8) ? sacc[k] : macc[k - 8];
#pragma unroll
    for (int off = 32; off > 0; off >>= 1) v += __shfl_down(v, off, 64);
    if (lane == 0) red[wv][k] = v;
  }
  __syncthreads();
  if (threadIdx.x < 44) {
    const float s = red[0][threadIdx.x] + red[1][threadIdx.x] +
                    red[2][threadIdx.x] + red[3][threadIdx.x];
    partOut[(size_t)bid2 * 88 + inp * 44 + threadIdx.x] = s;
  }
}

// One block per moment component; 256-thread tree reduction in double.
__global__ __launch_bounds__(256) void k1b_reduce(
    const float* __restrict__ part, double* __restrict__ mom)
{
  __shared__ double sd[256];
  const int t = blockIdx.x;              // 0..87
  double s = 0.0;
  for (int blk = threadIdx.x; blk < K1B; blk += 256)
    s += (double)part[(size_t)blk * 88 + t];
  sd[threadIdx.x] = s;
  __syncthreads();
  for (int off = 128; off > 0; off >>= 1) {
    if (threadIdx.x < off) sd[threadIdx.x] += sd[threadIdx.x + off];
    __syncthreads();
  }
  if (threadIdx.x == 0) mom[t] = sd[0];
}

// LN folded into the PFN weights (double precision):
//   z[o] = sum_c (a*w[o][c]) * x[c]  +  (beta + a*(bias - mean))
// par layout per input: awT[c][o] TRANSPOSED (c-major, 8x64) then zb[64].
// Transposed so channel pairs (o, o+1) at fixed c are ADJACENT -> SGPR pairs
// for v_pk_fma_f32 in k5f.
__global__ void k2_params(const double* __restrict__ mom,
    const float* __restrict__ w_s, const float* __restrict__ b_s,
    const float* __restrict__ g_s, const float* __restrict__ be_s,
    const float* __restrict__ w_m, const float* __restrict__ b_m,
    const float* __restrict__ g_m, const float* __restrict__ be_m,
    float* __restrict__ par)
{
  const int t = threadIdx.x;
  if (t >= 128) return;
  const int inp = t >> 6, o = t & 63;
  const double* m = mom + inp * 44;
  const float* w    = (inp ? w_m : w_s) + o * Cin;
  const float bias  = (inp ? b_m : b_s)[o];
  const float gamma = (inp ? g_m : g_s)[o];
  const float beta  = (inp ? be_m : be_s)[o];
  double S[8];
#pragma unroll
  for (int c = 0; c < 8; ++c) S[c] = m[c] / CNTD;
  double mean = (double)bias;
#pragma unroll
  for (int c = 0; c < 8; ++c) mean += (double)w[c] * S[c];
  double var = 0.0;
  int k = 8;
#pragma unroll
  for (int i = 0; i < 8; ++i)
#pragma unroll
    for (int j = i; j < 8; ++j) {
      const double cov = m[k] / CNTD - S[i] * S[j];
      const double ww = (double)w[i] * (double)w[j];
      var += (i == j ? ww : 2.0 * ww) * cov;
      ++k;
    }
  const double a = (double)gamma / sqrt(var + 1e-5);
  float* pr = par + inp * 576;
#pragma unroll
  for (int c = 0; c < 8; ++c) pr[c * 64 + o] = (float)(a * (double)w[c]);
  pr[512 + o] = (float)((double)beta + a * ((double)bias - mean));
}

// Union worklist of occupied cells (either input), BLOCK-ORDERED ballot scan
// with one atomicAdd per block -> wl entries stay tile-local for k_apply.
// Entry = {outbase, rowS | rowM<<16} (row = b*Pn + p < 48000; 0xFFFF = none).
// hdr[1]/hdr[2] keep per-input occupied counts (verdict diagnostic);
// hdr[3] = union count.
__global__ __launch_bounds__(256) void k_compact(
    const int* __restrict__ winners, int* __restrict__ hdr,
    int2* __restrict__ wlU)
{
  __shared__ int wcntU[4], cS[4], cM[4];
  __shared__ int baseU;
  const int t = blockIdx.x * 256 + threadIdx.x;
  const int lane = threadIdx.x & 63;
  const int wv   = threadIdx.x >> 6;
  int ps = -1, pm = -1, outbase = 0, b = 0;
  if (t < Bn * NCELL) {
    b = t / NCELL;
    const int hw = t - b * NCELL;
    outbase = b * Co * NCELL + hw;
    ps = winners[t];
    pm = winners[Bn * NCELL + t];
  }
  const bool occ = (ps >= 0) || (pm >= 0);
  const unsigned long long mu = __ballot(occ);
  const unsigned long long ms = __ballot(ps >= 0);
  const unsigned long long mm = __ballot(pm >= 0);
  if (lane == 0) {
    wcntU[wv] = __popcll(mu); cS[wv] = __popcll(ms); cM[wv] = __popcll(mm);
  }
  __syncthreads();
  if (threadIdx.x == 0) {
    const int c = wcntU[0] + wcntU[1] + wcntU[2] + wcntU[3];
    baseU = c ? atomicAdd(&hdr[3], c) : 0;
    const int s = cS[0] + cS[1] + cS[2] + cS[3];
    if (s) atomicAdd(&hdr[1], s);
  } else if (threadIdx.x == 64) {
    const int mcnt = cM[0] + cM[1] + cM[2] + cM[3];
    if (mcnt) atomicAdd(&hdr[2], mcnt);
  }
  __syncthreads();
  if (occ) {
    const unsigned long long below = (1ull << lane) - 1ull;
    int off = baseU + __popcll(mu & below);
    for (int w2 = 0; w2 < wv; ++w2) off += wcntU[w2];
    const unsigned rowS = (ps >= 0) ? (unsigned)(b * Pn + ps) : 0xFFFFu;
    const unsigned rowM = (pm >= 0) ? (unsigned)(b * Pn + pm) : 0xFFFFu;
    wlU[off] = make_int2(outbase, (int)(rowS | (rowM << 16)));
  }
}

// Transposed PFN, chunked, SGPR weights + PACKED FMA.
// One pillar per wave, lane = point index n: xv[c] lane-local (no broadcasts).
// Channels 8 at a time; per chunk one asm block s_loads the 8x8 transposed
// weight tile + 8 zb into SGPRs (scalar-cache hits, 4.6KB table shared by all
// waves). Matmul uses v_pk_fma_f32: adjacent channels (o,o+1) share one 64-bit
// accumulator; each half runs the identical fmaf chain (zb, c=0..7 ascending)
// -> values bit-identical to R5; issue count halves (512 -> 256 + dup movs).
// Reduce-scatter max tree unchanged from R5 (bit-identical).
__global__ __launch_bounds__(256) void k5f_feat(
    const float* __restrict__ sweep, const float* __restrict__ map_in,
    const float* __restrict__ par, const int* __restrict__ winners,
    float* __restrict__ feats)
{
  const int lane = threadIdx.x & 63;       // = n
  const int wv   = __builtin_amdgcn_readfirstlane(threadIdx.x >> 6);
  int pp = blockIdx.x * 4 + wv;
  const int inp = (pp >= NPIL) ? 1 : 0;
  pp -= inp * NPIL;
  const float* x   = inp ? map_in : sweep;
  const float* awT = par + inp * 576;      // [c][64] transposed
  const float* zbp = awT + 512;
  const int*   win = winners + inp * Bn * NCELL;
  float*       ft  = feats + (size_t)inp * NPIL * 64;

  const int b = pp / Pn;
  const int p = pp - b * Pn;
  const size_t base = (size_t)b * Cin * CHW + (size_t)p * Nn;

  float xv[Cin];
#pragma unroll
  for (int c = 0; c < Cin; ++c) xv[c] = x[base + (size_t)c * CHW + lane];

  const float xc0 = firstlane(xv[0]);
  if (xc0 == 0.0f) return;
  const float yc0 = firstlane(xv[1]);
  const int cell = cell_of(xc0, yc0);
  if (win[b * NCELL + cell] != p) return;

  f32x2_t xd[Cin];
#pragma unroll
  for (int c = 0; c < Cin; ++c) xd[c] = (f32x2_t){xv[c], xv[c]};

  const int l0 = lane & 1, l1 = (lane >> 1) & 1, l2 = (lane >> 2) & 1;
  float res = 0.f;
#pragma unroll
  for (int g = 0; g < 8; ++g) {
    f32x8_t wr0, wr1, wr2, wr3, wr4, wr5, wr6, wr7, zb8;
    asm("s_load_dwordx8 %0, %9, 0x0\n\t"
        "s_load_dwordx8 %1, %9, 0x100\n\t"
        "s_load_dwordx8 %2, %9, 0x200\n\t"
        "s_load_dwordx8 %3, %9, 0x300\n\t"
        "s_load_dwordx8 %4, %9, 0x400\n\t"
        "s_load_dwordx8 %5, %9, 0x500\n\t"
        "s_load_dwordx8 %6, %9, 0x600\n\t"
        "s_load_dwordx8 %7, %9, 0x700\n\t"
        "s_load_dwordx8 %8, %10, 0x0\n\t"
        "s_waitcnt lgkmcnt(0)"
        : "=&s"(wr0), "=&s"(wr1), "=&s"(wr2), "=&s"(wr3), "=&s"(wr4),
          "=&s"(wr5), "=&s"(wr6), "=&s"(wr7), "=&s"(zb8)
        : "s"(awT + g * 8), "s"(zbp + g * 8));

    f32x2_t y0 = {zb8[0], zb8[1]};
    f32x2_t y1 = {zb8[2], zb8[3]};
    f32x2_t y2 = {zb8[4], zb8[5]};
    f32x2_t y3 = {zb8[6], zb8[7]};
#define CH(C, W)                                                              \
    {                                                                         \
      f32x2_t wpa = {W[0], W[1]}, wpb = {W[2], W[3]};                         \
      f32x2_t wpc = {W[4], W[5]}, wpd = {W[6], W[7]};                         \
      asm("v_pk_fma_f32 %0, %1, %2, %0" : "+v"(y0) : "s"(wpa), "v"(xd[C]));   \
      asm("v_pk_fma_f32 %0, %1, %2, %0" : "+v"(y1) : "s"(wpb), "v"(xd[C]));   \
      asm("v_pk_fma_f32 %0, %1, %2, %0" : "+v"(y2) : "s"(wpc), "v"(xd[C]));   \
      asm("v_pk_fma_f32 %0, %1, %2, %0" : "+v"(y3) : "s"(wpd), "v"(xd[C]));   \
    }
    CH(0, wr0) CH(1, wr1) CH(2, wr2) CH(3, wr3)
    CH(4, wr4) CH(5, wr5) CH(6, wr6) CH(7, wr7)
#undef CH
    float z[8] = {y0[0], y0[1], y1[0], y1[1], y2[0], y2[1], y3[0], y3[1]};

    // item-halving rounds: slot ends holding item j = lane&7
    float t0[4];
#pragma unroll
    for (int i = 0; i < 4; ++i) {
      const float send = l0 ? z[2 * i] : z[2 * i + 1];
      const float keep = l0 ? z[2 * i + 1] : z[2 * i];
      t0[i] = fmaxf(keep, __shfl_xor(send, 1, 64));
    }
    float t1[2];
#pragma unroll
    for (int i = 0; i < 2; ++i) {
      const float send = l1 ? t0[2 * i] : t0[2 * i + 1];
      const float keep = l1 ? t0[2 * i + 1] : t0[2 * i];
      t1[i] = fmaxf(keep, __shfl_xor(send, 2, 64));
    }
    {
      const float send = l2 ? t1[0] : t1[1];
      const float keep = l2 ? t1[1] : t1[0];
      float v = fmaxf(keep, __shfl_xor(send, 4, 64));
      // fold over lane groups
      v = fmaxf(v, __shfl_xor(v, 8, 64));
      v = fmaxf(v, __shfl_xor(v, 16, 64));
      v = fmaxf(v, __shfl_xor(v, 32, 64));
      if ((lane >> 3) == g) res = v;
    }
  }
  ft[(size_t)pp * 64 + lane] = fmaxf(res, 0.f);
}

// Dense matvec over the UNION worklist: one pass computes
//   out[o] = bias[o] + W[:,0:64]·fs + W[:,64:128]·fm
// with fs/fm = 0 when that input has no winner in the cell (the original
// k_out also ran its fmaf chain on zeros -> bit-identical), single write.
__global__ __launch_bounds__(256) void k_apply(
    const int* __restrict__ hdr, const int2* __restrict__ wl,
    const float* __restrict__ feats, const float* __restrict__ w_bb,
    const float* __restrict__ b_bb, float* __restrict__ out)
{
  __shared__ float4 wlds[Co * 32];
  __shared__ float bbb[Co];
  for (int i = threadIdx.x; i < Co * 32; i += 256)
    wlds[i] = ((const float4*)w_bb)[i];
  if (threadIdx.x < Co) bbb[threadIdx.x] = b_bb[threadIdx.x];
  __syncthreads();
  const int cnt = hdr[3];
  for (int i = blockIdx.x * blockDim.x + threadIdx.x; i < cnt;
       i += gridDim.x * blockDim.x) {
    const int2 e = wl[i];
    const unsigned pk = (unsigned)e.y;
    const unsigned rowS = pk & 0xFFFFu;
    const unsigned rowM = pk >> 16;
    float4 fs[16], fm[16];
    if (rowS != 0xFFFFu) {
      const float4* f = (const float4*)(feats + (size_t)rowS * 64);
#pragma unroll
      for (int k = 0; k < 16; ++k) fs[k] = f[k];
    } else {
#pragma unroll
      for (int k = 0; k < 16; ++k) fs[k] = make_float4(0.f, 0.f, 0.f, 0.f);
    }
    if (rowM != 0xFFFFu) {
      const float4* f = (const float4*)(feats + (size_t)NPIL * 64 + (size_t)rowM * 64);
#pragma unroll
      for (int k = 0; k < 16; ++k) fm[k] = f[k];
    } else {
#pragma unroll
      for (int k = 0; k < 16; ++k) fm[k] = make_float4(0.f, 0.f, 0.f, 0.f);
    }
    float* op = out + e.x;
#pragma unroll 2
    for (int o = 0; o < Co; ++o) {
      float acc = bbb[o];
      const float4* row = &wlds[o * 32];
#pragma unroll
      for (int k = 0; k < 16; ++k) {
        const float4 w4 = row[k];
        acc = fmaf(w4.x, fs[k].x, acc); acc = fmaf(w4.y, fs[k].y, acc);
        acc = fmaf(w4.z, fs[k].z, acc); acc = fmaf(w4.w, fs[k].w, acc);
      }
#pragma unroll
      for (int k = 0; k < 16; ++k) {
        const float4 w4 = row[16 + k];
        acc = fmaf(w4.x, fm[k].x, acc); acc = fmaf(w4.y, fm[k].y, acc);
        acc = fmaf(w4.z, fm[k].z, acc); acc = fmaf(w4.w, fm[k].w, acc);
      }
      op[(size_t)o * NCELL] = acc;
    }
  }
}

__global__ void k6_verdict(const int* __restrict__ hdr, float* __restrict__ out)
{
  if (threadIdx.x != 0 || blockIdx.x != 0) return;
  const int n_occ = hdr[1] + hdr[2];
  if (n_occ < 80000 || n_occ > 96000) out[0] = 1.0e7f + (float)n_occ;
}

extern "C" void kernel_launch(void* const* d_in, const int* in_sizes, int n_in,
                              void* d_out, int out_size, void* d_ws, size_t ws_size,
                              hipStream_t stream)
{
  const float* sweep  = (const float*)d_in[0];
  const float* map_in = (const float*)d_in[1];
  const float* w_s  = (const float*)d_in[2];
  const float* b_s  = (const float*)d_in[3];
  const float* g_s  = (const float*)d_in[4];
  const float* be_s = (const float*)d_in[5];
  const float* w_m  = (const float*)d_in[6];
  const float* b_m  = (const float*)d_in[7];
  const float* g_m  = (const float*)d_in[8];
  const float* be_m = (const float*)d_in[9];
  const float* w_bb = (const float*)d_in[10];
  const float* b_bb = (const float*)d_in[11];
  float* out = (float*)d_out;

  const int exp_sz[12] = {24576000, 24576000, 512, 64, 64, 64, 512, 64, 64, 64, 8192, 64};
  int bad_idx = -1;
  if (n_in != 12) bad_idx = 11;
  else for (int i = 0; i < 12; ++i) if (in_sizes[i] != exp_sz[i]) { bad_idx = i; break; }
  if (bad_idx >= 0) {
    kdiag<<<1, 1, 0, stream>>>(out, 9.0e7f + 1.0e5f * (float)bad_idx);
    return;
  }
  if (ws_size < WS_NEED) {
    kdiag<<<1, 1, 0, stream>>>(out, 8.0e7f);
    return;
  }

  char* ws = (char*)d_ws;
  float*  par     = (float*)(ws + PAR_OFF);
  double* mom     = (double*)(ws + MOM_OFF);
  int*    hdr     = (int*)(ws + HDR_OFF);
  int*    winners = (int*)(ws + WIN_OFF);
  float*  feats   = (float*)(ws + FEAT_OFF);
  float*  part    = (float*)(ws + PART_OFF);
  int2*   wlU     = (int2*)(ws + WLU_OFF);

  kinit_fill<<<FILL_B + 256, 256, 0, stream>>>(b_bb, out, winners, hdr);
  k1_mom<<<2 * K1B, 256, 0, stream>>>(sweep, map_in, part, winners);
  k1b_reduce<<<88, 256, 0, stream>>>(part, mom);
  k2_params<<<1, 128, 0, stream>>>(mom, w_s, b_s, g_s, be_s, w_m, b_m, g_m, be_m, par);
  k_compact<<<(Bn * NCELL + 255) / 256, 256, 0, stream>>>(winners, hdr, wlU);
  k5f_feat<<<2 * NPIL / 4, 256, 0, stream>>>(sweep, map_in, par, winners, feats);
  k_apply<<<WLU_CAP / 256, 256, 0, stream>>>(hdr, wlU, feats, w_bb, b_bb, out);
  k6_verdict<<<1, 1, 0, stream>>>(hdr, out);
}

// Round 7
// 321.555 us; speedup vs baseline: 1.1437x; 1.1437x over previous
//
#include <hip/hip_runtime.h>
#include <cfloat>
#include <math.h>

namespace {
constexpr int Bn = 4, Cin = 8, Pn = 12000, Nn = 64, Co = 64, Hh = 282, Ww = 282;
constexpr int NPIL  = Bn * Pn;
constexpr int NCELL = Hh * Ww;
constexpr int CHW   = Pn * Nn;
constexpr double CNTD = (double)Bn * Pn * Nn;
constexpr int K1B = 1024;               // k1_mom blocks per input (8 waves/SIMD)
constexpr int WL_CAP = 48000;           // max occupied cells per input
constexpr int APPLY_B = (WL_CAP + 255) / 256;
constexpr int FILL_B = (Bn * Co * NCELL / 4) / 256;   // 19881, exact

// Workspace layout. part (k1_mom partials) aliases the feats region: it is
// dead after k1b_reduce, before k5f_feat writes feats.
constexpr size_t PAR_OFF  = 0;                          // 2*576 floats = 4608
constexpr size_t MOM_OFF  = 4608;                       // 88 doubles   = 704
constexpr size_t HDR_OFF  = 5376;                       // 4 ints
constexpr size_t WLS_OFF  = 8192;                       // WL_CAP int2 = 384000
constexpr size_t WLM_OFF  = WLS_OFF + (size_t)WL_CAP * 8;    // 392192
constexpr size_t WIN_OFF  = WLM_OFF + (size_t)WL_CAP * 8;    // 776192
constexpr size_t FEAT_OFF = WIN_OFF + (size_t)2 * Bn * NCELL * 4; // 3320960
constexpr size_t PART_OFF = FEAT_OFF;                   // alias (see above)
constexpr size_t WS_NEED  = FEAT_OFF + (size_t)2 * NPIL * 64 * 4; // 27896960

typedef __attribute__((ext_vector_type(8))) float f32x8_t;
typedef __attribute__((ext_vector_type(2))) float f32x2_t;

// Grid mapping matched to XLA's canonicalization: division by 0.16 becomes
// multiplication by the EXACT reciprocal 6.25 (rcp(0.16f) rounds to 6.25f).
// f32-div differs by ~0.3ulp -> O(1) pillars land one cell off (the 2.62 bug).
__device__ __forceinline__ int cell_of(float xc, float yc) {
  int xg = (int)floorf((xc + 22.0f) * 6.25f);
  int yg = (int)floorf((yc + 22.0f) * 6.25f);
  xg = min(max(xg, 0), Ww - 1);
  yg = min(max(yg, 0), Hh - 1);
  return yg * Ww + xg;
}

__device__ __forceinline__ float firstlane(float v) {
  return __int_as_float(__builtin_amdgcn_readfirstlane(__float_as_int(v)));
}

// Cross-lane xor-1 / xor-2 on the VALU via DPP quad_perm (no DS pipe).
// 0xB1 = [1,0,3,2] (lane^1), 0x4E = [2,3,0,1] (lane^2). All lanes active in
// the winner path -> identical values to __shfl_xor.
__device__ __forceinline__ float dpp_xor1(float v) {
  return __int_as_float(__builtin_amdgcn_update_dpp(
      0, __float_as_int(v), 0xB1, 0xF, 0xF, true));
}
__device__ __forceinline__ float dpp_xor2(float v) {
  return __int_as_float(__builtin_amdgcn_update_dpp(
      0, __float_as_int(v), 0x4E, 0xF, 0xF, true));
}
}

__global__ void kdiag(float* __restrict__ out, float v) {
  if (threadIdx.x == 0 && blockIdx.x == 0) out[0] = v;
}

// Merged bias-fill (blocks [0,FILL_B)) + winners/hdr init (blocks >= FILL_B).
__global__ __launch_bounds__(256) void kinit_fill(
    const float* __restrict__ b_bb, float* __restrict__ out,
    int* __restrict__ winners, int* __restrict__ hdr)
{
  if (blockIdx.x < FILL_B) {
    const int idx = blockIdx.x * 256 + threadIdx.x;
    const int plane = idx / (NCELL / 4);      // b*Co + o
    const float v = b_bb[plane & 63];
    ((float4*)out)[idx] = make_float4(v, v, v, v);
  } else {
    const int t = (blockIdx.x - FILL_B) * 256 + threadIdx.x;
    if (t < 4) hdr[t] = 0;
    for (int i = t; i < 2 * Bn * NCELL; i += 256 * 256) winners[i] = -1;
  }
}

// Merged over both inputs: blocks [0,K1B) -> sweep, [K1B,2*K1B) -> map.
// Memory-bound streaming pass; pillar->cell scatter fused in (lane 0 already
// holds xc/yc): one atomicMax per pillar.
__global__ __launch_bounds__(256) void k1_mom(
    const float* __restrict__ sweep, const float* __restrict__ map_in,
    float* __restrict__ partOut, int* __restrict__ winners)
{
  __shared__ float red[4][44];
  const int lane = threadIdx.x & 63;
  const int wv   = threadIdx.x >> 6;
  const int bid2 = blockIdx.x & (K1B - 1);
  const int inp  = blockIdx.x / K1B;
  const float* x = inp ? map_in : sweep;
  int* win = winners + inp * Bn * NCELL;
  const int gw   = (bid2 * 256 + (int)threadIdx.x) >> 6;
  const int nw   = (K1B * 256) >> 6;

  float sacc[8];
  float macc[36];
#pragma unroll
  for (int i = 0; i < 8; ++i) sacc[i] = 0.f;
#pragma unroll
  for (int i = 0; i < 36; ++i) macc[i] = 0.f;

  for (int pp = gw; pp < NPIL; pp += nw) {
    const int b = pp / Pn;
    const int p = pp - b * Pn;
    const float* xb = x + (size_t)b * Cin * CHW + (size_t)p * Nn + lane;
    float xv[Cin];
#pragma unroll
    for (int c = 0; c < Cin; ++c) xv[c] = xb[(size_t)c * CHW];
#pragma unroll
    for (int c = 0; c < Cin; ++c) sacc[c] += xv[c];
    {
      int k = 0;
#pragma unroll
      for (int i = 0; i < 8; ++i)
#pragma unroll
        for (int j = i; j < 8; ++j) { macc[k] = fmaf(xv[i], xv[j], macc[k]); ++k; }
    }
    // Fused scatter: xc = x[base] = lane 0's xv[0], yc = lane 0's xv[1].
    const float xc = firstlane(xv[0]);
    if (xc != 0.0f) {
      const float yc = firstlane(xv[1]);
      if (lane == 0) atomicMax(&win[b * NCELL + cell_of(xc, yc)], p);
    }
  }

#pragma unroll
  for (int k = 0; k < 44; ++k) {
    float v = (k < 8) ? sacc[k] : macc[k - 8];
#pragma unroll
    for (int off = 32; off > 0; off >>= 1) v += __shfl_down(v, off, 64);
    if (lane == 0) red[wv][k] = v;
  }
  __syncthreads();
  if (threadIdx.x < 44) {
    const float s = red[0][threadIdx.x] + red[1][threadIdx.x] +
                    red[2][threadIdx.x] + red[3][threadIdx.x];
    partOut[(size_t)bid2 * 88 + inp * 44 + threadIdx.x] = s;
  }
}

// One block per moment component; 256-thread tree reduction in double.
__global__ __launch_bounds__(256) void k1b_reduce(
    const float* __restrict__ part, double* __restrict__ mom)
{
  __shared__ double sd[256];
  const int t = blockIdx.x;              // 0..87
  double s = 0.0;
  for (int blk = threadIdx.x; blk < K1B; blk += 256)
    s += (double)part[(size_t)blk * 88 + t];
  sd[threadIdx.x] = s;
  __syncthreads();
  for (int off = 128; off > 0; off >>= 1) {
    if (threadIdx.x < off) sd[threadIdx.x] += sd[threadIdx.x + off];
    __syncthreads();
  }
  if (threadIdx.x == 0) mom[t] = sd[0];
}

// LN folded into the PFN weights (double precision):
//   z[o] = sum_c (a*w[o][c]) * x[c]  +  (beta + a*(bias - mean))
// par layout per input: awT[c][o] TRANSPOSED (c-major, 8x64) then zb[64].
// Transposed so channel pairs (o, o+1) at fixed c are ADJACENT -> SGPR pairs
// for v_pk_fma_f32 in k5f.
__global__ void k2_params(const double* __restrict__ mom,
    const float* __restrict__ w_s, const float* __restrict__ b_s,
    const float* __restrict__ g_s, const float* __restrict__ be_s,
    const float* __restrict__ w_m, const float* __restrict__ b_m,
    const float* __restrict__ g_m, const float* __restrict__ be_m,
    float* __restrict__ par)
{
  const int t = threadIdx.x;
  if (t >= 128) return;
  const int inp = t >> 6, o = t & 63;
  const double* m = mom + inp * 44;
  const float* w    = (inp ? w_m : w_s) + o * Cin;
  const float bias  = (inp ? b_m : b_s)[o];
  const float gamma = (inp ? g_m : g_s)[o];
  const float beta  = (inp ? be_m : be_s)[o];
  double S[8];
#pragma unroll
  for (int c = 0; c < 8; ++c) S[c] = m[c] / CNTD;
  double mean = (double)bias;
#pragma unroll
  for (int c = 0; c < 8; ++c) mean += (double)w[c] * S[c];
  double var = 0.0;
  int k = 8;
#pragma unroll
  for (int i = 0; i < 8; ++i)
#pragma unroll
    for (int j = i; j < 8; ++j) {
      const double cov = m[k] / CNTD - S[i] * S[j];
      const double ww = (double)w[i] * (double)w[j];
      var += (i == j ? ww : 2.0 * ww) * cov;
      ++k;
    }
  const double a = (double)gamma / sqrt(var + 1e-5);
  float* pr = par + inp * 576;
#pragma unroll
  for (int c = 0; c < 8; ++c) pr[c * 64 + o] = (float)(a * (double)w[c]);
  pr[512 + o] = (float)((double)beta + a * ((double)bias - mean));
}

// Build packed worklists (per input), BLOCK-ORDERED: ballot scan + one
// atomicAdd per block per list -> wl entries stay tile-local for k_apply.
// Entry = {outbase = b*Co*NCELL + hw, featrow = b*Pn + p}.
// hdr[1]/hdr[2] double as the occupancy diagnostic.
__global__ __launch_bounds__(256) void k_compact(
    const int* __restrict__ winners, int* __restrict__ hdr,
    int2* __restrict__ wlS, int2* __restrict__ wlM)
{
  __shared__ int cS[4], cM[4];
  __shared__ int baseS, baseM;
  const int t = blockIdx.x * 256 + threadIdx.x;
  const int lane = threadIdx.x & 63;
  const int wv   = threadIdx.x >> 6;
  int ps = -1, pm = -1, outbase = 0, b = 0;
  if (t < Bn * NCELL) {
    b = t / NCELL;
    const int hw = t - b * NCELL;
    outbase = b * Co * NCELL + hw;
    ps = winners[t];
    pm = winners[Bn * NCELL + t];
  }
  const unsigned long long ms = __ballot(ps >= 0);
  const unsigned long long mm = __ballot(pm >= 0);
  if (lane == 0) { cS[wv] = __popcll(ms); cM[wv] = __popcll(mm); }
  __syncthreads();
  if (threadIdx.x == 0) {
    const int c = cS[0] + cS[1] + cS[2] + cS[3];
    baseS = c ? atomicAdd(&hdr[1], c) : 0;
  } else if (threadIdx.x == 64) {
    const int c = cM[0] + cM[1] + cM[2] + cM[3];
    baseM = c ? atomicAdd(&hdr[2], c) : 0;
  }
  __syncthreads();
  const unsigned long long below = (1ull << lane) - 1ull;
  if (ps >= 0) {
    int off = baseS + __popcll(ms & below);
    for (int w2 = 0; w2 < wv; ++w2) off += cS[w2];
    wlS[off] = make_int2(outbase, b * Pn + ps);
  }
  if (pm >= 0) {
    int off = baseM + __popcll(mm & below);
    for (int w2 = 0; w2 < wv; ++w2) off += cM[w2];
    wlM[off] = make_int2(outbase, b * Pn + pm);
  }
}

// Transposed PFN, chunked, SGPR weights + packed FMA + DPP reduce.
// One pillar per wave, lane = point index n: xv[c] lane-local (no broadcasts).
// Channels 8 at a time; per chunk one asm block s_loads the 8x8 transposed
// weight tile + 8 zb into SGPRs (scalar-cache hits). Matmul: v_pk_fma_f32,
// channel pairs (o,o+1) share a 64-bit accumulator, each half runs the
// identical fmaf chain -> bit-identical values. Reduce: same DAG as R5/R6 but
// xor1/xor2 rounds use DPP quad_perm (VALU) instead of DS shuffles -- DS ops
// drop from 10 to 4 per chunk (xor4 + the three folds remain DS).
__global__ __launch_bounds__(256) void k5f_feat(
    const float* __restrict__ sweep, const float* __restrict__ map_in,
    const float* __restrict__ par, const int* __restrict__ winners,
    float* __restrict__ feats)
{
  const int lane = threadIdx.x & 63;       // = n
  const int wv   = __builtin_amdgcn_readfirstlane(threadIdx.x >> 6);
  int pp = blockIdx.x * 4 + wv;
  const int inp = (pp >= NPIL) ? 1 : 0;
  pp -= inp * NPIL;
  const float* x   = inp ? map_in : sweep;
  const float* awT = par + inp * 576;      // [c][64] transposed
  const float* zbp = awT + 512;
  const int*   win = winners + inp * Bn * NCELL;
  float*       ft  = feats + (size_t)inp * NPIL * 64;

  const int b = pp / Pn;
  const int p = pp - b * Pn;
  const size_t base = (size_t)b * Cin * CHW + (size_t)p * Nn;

  float xv[Cin];
#pragma unroll
  for (int c = 0; c < Cin; ++c) xv[c] = x[base + (size_t)c * CHW + lane];

  const float xc0 = firstlane(xv[0]);
  if (xc0 == 0.0f) return;
  const float yc0 = firstlane(xv[1]);
  const int cell = cell_of(xc0, yc0);
  if (win[b * NCELL + cell] != p) return;

  f32x2_t xd[Cin];
#pragma unroll
  for (int c = 0; c < Cin; ++c) xd[c] = (f32x2_t){xv[c], xv[c]};

  const int l0 = lane & 1, l1 = (lane >> 1) & 1, l2 = (lane >> 2) & 1;
  float res = 0.f;
#pragma unroll
  for (int g = 0; g < 8; ++g) {
    f32x8_t wr0, wr1, wr2, wr3, wr4, wr5, wr6, wr7, zb8;
    asm("s_load_dwordx8 %0, %9, 0x0\n\t"
        "s_load_dwordx8 %1, %9, 0x100\n\t"
        "s_load_dwordx8 %2, %9, 0x200\n\t"
        "s_load_dwordx8 %3, %9, 0x300\n\t"
        "s_load_dwordx8 %4, %9, 0x400\n\t"
        "s_load_dwordx8 %5, %9, 0x500\n\t"
        "s_load_dwordx8 %6, %9, 0x600\n\t"
        "s_load_dwordx8 %7, %9, 0x700\n\t"
        "s_load_dwordx8 %8, %10, 0x0\n\t"
        "s_waitcnt lgkmcnt(0)"
        : "=&s"(wr0), "=&s"(wr1), "=&s"(wr2), "=&s"(wr3), "=&s"(wr4),
          "=&s"(wr5), "=&s"(wr6), "=&s"(wr7), "=&s"(zb8)
        : "s"(awT + g * 8), "s"(zbp + g * 8));

    f32x2_t y0 = {zb8[0], zb8[1]};
    f32x2_t y1 = {zb8[2], zb8[3]};
    f32x2_t y2 = {zb8[4], zb8[5]};
    f32x2_t y3 = {zb8[6], zb8[7]};
#define CH(C, W)                                                              \
    {                                                                         \
      f32x2_t wpa = {W[0], W[1]}, wpb = {W[2], W[3]};                         \
      f32x2_t wpc = {W[4], W[5]}, wpd = {W[6], W[7]};                         \
      asm("v_pk_fma_f32 %0, %1, %2, %0" : "+v"(y0) : "s"(wpa), "v"(xd[C]));   \
      asm("v_pk_fma_f32 %0, %1, %2, %0" : "+v"(y1) : "s"(wpb), "v"(xd[C]));   \
      asm("v_pk_fma_f32 %0, %1, %2, %0" : "+v"(y2) : "s"(wpc), "v"(xd[C]));   \
      asm("v_pk_fma_f32 %0, %1, %2, %0" : "+v"(y3) : "s"(wpd), "v"(xd[C]));   \
    }
    CH(0, wr0) CH(1, wr1) CH(2, wr2) CH(3, wr3)
    CH(4, wr4) CH(5, wr5) CH(6, wr6) CH(7, wr7)
#undef CH
    float z[8] = {y0[0], y0[1], y1[0], y1[1], y2[0], y2[1], y3[0], y3[1]};

    // item-halving rounds: slot ends holding item j = lane&7
    float t0[4];
#pragma unroll
    for (int i = 0; i < 4; ++i) {
      const float send = l0 ? z[2 * i] : z[2 * i + 1];
      const float keep = l0 ? z[2 * i + 1] : z[2 * i];
      t0[i] = fmaxf(keep, dpp_xor1(send));
    }
    float t1[2];
#pragma unroll
    for (int i = 0; i < 2; ++i) {
      const float send = l1 ? t0[2 * i] : t0[2 * i + 1];
      const float keep = l1 ? t0[2 * i + 1] : t0[2 * i];
      t1[i] = fmaxf(keep, dpp_xor2(send));
    }
    {
      const float send = l2 ? t1[0] : t1[1];
      const float keep = l2 ? t1[1] : t1[0];
      float v = fmaxf(keep, __shfl_xor(send, 4, 64));
      // fold over lane groups
      v = fmaxf(v, __shfl_xor(v, 8, 64));
      v = fmaxf(v, __shfl_xor(v, 16, 64));
      v = fmaxf(v, __shfl_xor(v, 32, 64));
      if ((lane >> 3) == g) res = v;
    }
  }
  ft[(size_t)pp * 64 + lane] = fmaxf(res, 0.f);
}

// Dense matvec over the compacted worklist (split pair, R5 structure).
// WHICH=0 (sweep): out[o] = bias[o] + W[:,0:64]·f   (overwrite after fill)
// WHICH=1 (map):   out[o] +=          W[:,64:128]·f (RMW, runs after WHICH=0)
// fmaf ordering identical to the original fused kernel -> bit-identical.
template<int WHICH>
__global__ __launch_bounds__(256) void k_apply(
    const int* __restrict__ hdr, const int2* __restrict__ wl,
    const float* __restrict__ feats, const float* __restrict__ w_bb,
    const float* __restrict__ b_bb, float* __restrict__ out)
{
  __shared__ float4 wlds[Co * 16];
  __shared__ float bbb[Co];
  for (int i = threadIdx.x; i < Co * 16; i += 256)
    wlds[i] = ((const float4*)w_bb)[((i >> 4) << 5) + (WHICH ? 16 : 0) + (i & 15)];
  if (threadIdx.x < Co) bbb[threadIdx.x] = b_bb[threadIdx.x];
  __syncthreads();
  const int cnt = hdr[1 + WHICH];
  for (int i = blockIdx.x * blockDim.x + threadIdx.x; i < cnt;
       i += gridDim.x * blockDim.x) {
    const int2 e = wl[i];
    const float4* fp = (const float4*)(feats + (size_t)e.y * 64);
    float4 f[16];
#pragma unroll
    for (int k = 0; k < 16; ++k) f[k] = fp[k];
    float* op = out + e.x;
#pragma unroll 2
    for (int o = 0; o < Co; ++o) {
      float acc = WHICH ? op[(size_t)o * NCELL] : bbb[o];
      const float4* row = &wlds[o * 16];
#pragma unroll
      for (int k = 0; k < 16; ++k) {
        const float4 w4 = row[k];
        acc = fmaf(w4.x, f[k].x, acc); acc = fmaf(w4.y, f[k].y, acc);
        acc = fmaf(w4.z, f[k].z, acc); acc = fmaf(w4.w, f[k].w, acc);
      }
      op[(size_t)o * NCELL] = acc;
    }
  }
}

__global__ void k6_verdict(const int* __restrict__ hdr, float* __restrict__ out)
{
  if (threadIdx.x != 0 || blockIdx.x != 0) return;
  const int n_occ = hdr[1] + hdr[2];
  if (n_occ < 80000 || n_occ > 96000) out[0] = 1.0e7f + (float)n_occ;
}

extern "C" void kernel_launch(void* const* d_in, const int* in_sizes, int n_in,
                              void* d_out, int out_size, void* d_ws, size_t ws_size,
                              hipStream_t stream)
{
  const float* sweep  = (const float*)d_in[0];
  const float* map_in = (const float*)d_in[1];
  const float* w_s  = (const float*)d_in[2];
  const float* b_s  = (const float*)d_in[3];
  const float* g_s  = (const float*)d_in[4];
  const float* be_s = (const float*)d_in[5];
  const float* w_m  = (const float*)d_in[6];
  const float* b_m  = (const float*)d_in[7];
  const float* g_m  = (const float*)d_in[8];
  const float* be_m = (const float*)d_in[9];
  const float* w_bb = (const float*)d_in[10];
  const float* b_bb = (const float*)d_in[11];
  float* out = (float*)d_out;

  const int exp_sz[12] = {24576000, 24576000, 512, 64, 64, 64, 512, 64, 64, 64, 8192, 64};
  int bad_idx = -1;
  if (n_in != 12) bad_idx = 11;
  else for (int i = 0; i < 12; ++i) if (in_sizes[i] != exp_sz[i]) { bad_idx = i; break; }
  if (bad_idx >= 0) {
    kdiag<<<1, 1, 0, stream>>>(out, 9.0e7f + 1.0e5f * (float)bad_idx);
    return;
  }
  if (ws_size < WS_NEED) {
    kdiag<<<1, 1, 0, stream>>>(out, 8.0e7f);
    return;
  }

  char* ws = (char*)d_ws;
  float*  par     = (float*)(ws + PAR_OFF);
  double* mom     = (double*)(ws + MOM_OFF);
  int*    hdr     = (int*)(ws + HDR_OFF);
  int*    winners = (int*)(ws + WIN_OFF);
  float*  feats   = (float*)(ws + FEAT_OFF);
  float*  part    = (float*)(ws + PART_OFF);
  int2*   wlS     = (int2*)(ws + WLS_OFF);
  int2*   wlM     = (int2*)(ws + WLM_OFF);

  kinit_fill<<<FILL_B + 256, 256, 0, stream>>>(b_bb, out, winners, hdr);
  k1_mom<<<2 * K1B, 256, 0, stream>>>(sweep, map_in, part, winners);
  k1b_reduce<<<88, 256, 0, stream>>>(part, mom);
  k2_params<<<1, 128, 0, stream>>>(mom, w_s, b_s, g_s, be_s, w_m, b_m, g_m, be_m, par);
  k_compact<<<(Bn * NCELL + 255) / 256, 256, 0, stream>>>(winners, hdr, wlS, wlM);
  k5f_feat<<<2 * NPIL / 4, 256, 0, stream>>>(sweep, map_in, par, winners, feats);
  k_apply<0><<<APPLY_B, 256, 0, stream>>>(hdr, wlS, feats, w_bb, b_bb, out);
  k_apply<1><<<APPLY_B, 256, 0, stream>>>(hdr, wlM, feats + (size_t)NPIL * 64,
                                          w_bb, b_bb, out);
  k6_verdict<<<1, 1, 0, stream>>>(hdr, out);
}